// Round 1
// baseline (23551.106 us; speedup 1.0000x reference)
//
#include <hip/hip_runtime.h>

#define H 100
#define FIN 2
#define KORD 5

// ---------------- graph setup ----------------

__global__ __launch_bounds__(256) void deg_kernel(const int* __restrict__ src, const int* __restrict__ dst,
                                                  float* __restrict__ deg, int* __restrict__ indeg, int E) {
  int e = blockIdx.x * 256 + threadIdx.x;
  if (e < E) {
    atomicAdd(&deg[src[e]], 1.0f);
    atomicAdd(&indeg[dst[e]], 1);
  }
}

__global__ __launch_bounds__(256) void dinv_kernel(const float* __restrict__ deg, float* __restrict__ dinv, int n) {
  int i = blockIdx.x * 256 + threadIdx.x;
  if (i < n) {
    float d = deg[i];
    dinv[i] = d > 0.f ? rsqrtf(fmaxf(d, 1.f)) : 0.f;
  }
}

__global__ __launch_bounds__(256) void scan_block(const int* __restrict__ in, int* __restrict__ incl,
                                                  int* __restrict__ bsum, int n) {
  __shared__ int s[256];
  int i = blockIdx.x * 256 + threadIdx.x;
  int v = (i < n) ? in[i] : 0;
  s[threadIdx.x] = v;
  __syncthreads();
  for (int d = 1; d < 256; d <<= 1) {
    int t = (threadIdx.x >= d) ? s[threadIdx.x - d] : 0;
    __syncthreads();
    s[threadIdx.x] += t;
    __syncthreads();
  }
  if (i < n) incl[i] = s[threadIdx.x];
  if (threadIdx.x == 255) bsum[blockIdx.x] = s[255];
}

__global__ __launch_bounds__(256) void scan_sums(const int* __restrict__ bsum, int* __restrict__ bscan, int nb) {
  __shared__ int s[256];
  __shared__ int carry;
  if (threadIdx.x == 0) carry = 0;
  __syncthreads();
  for (int base = 0; base < nb; base += 256) {
    int i = base + threadIdx.x;
    int v = (i < nb) ? bsum[i] : 0;
    s[threadIdx.x] = v;
    __syncthreads();
    for (int d = 1; d < 256; d <<= 1) {
      int t = (threadIdx.x >= d) ? s[threadIdx.x - d] : 0;
      __syncthreads();
      s[threadIdx.x] += t;
      __syncthreads();
    }
    int c = carry;
    if (i < nb) bscan[i] = s[threadIdx.x] + c;
    __syncthreads();
    if (threadIdx.x == 0) carry = c + s[255];
    __syncthreads();
  }
}

__global__ __launch_bounds__(256) void finalize_offsets(const int* __restrict__ incl, const int* __restrict__ indeg,
                                                        const int* __restrict__ bscan, int* __restrict__ offsets,
                                                        int* __restrict__ cursor, int n, int total) {
  int i = blockIdx.x * 256 + threadIdx.x;
  if (i < n) {
    int prev = (blockIdx.x > 0) ? bscan[blockIdx.x - 1] : 0;
    int excl = incl[i] - indeg[i] + prev;
    offsets[i] = excl;
    cursor[i] = excl;
  }
  if (i == 0) offsets[n] = total;
}

__global__ __launch_bounds__(256) void build_csr(const int* __restrict__ src, const int* __restrict__ dst,
                                                 const float* __restrict__ dinv, int* __restrict__ cursor,
                                                 int* __restrict__ csr_src, float* __restrict__ csr_norm, int E) {
  int e = blockIdx.x * 256 + threadIdx.x;
  if (e < E) {
    int s = src[e], d = dst[e];
    float nrm = -dinv[s] * dinv[d];
    int p = atomicAdd(&cursor[d], 1);
    csr_src[p] = s;
    csr_norm[p] = nrm;
  }
}

// ---------------- propagate ----------------

// F=2 props for layer 0 (thread per node)
__global__ __launch_bounds__(256) void prop2(const float* __restrict__ h, const float* __restrict__ prev,
                                             float* __restrict__ out, const int* __restrict__ offs,
                                             const int* __restrict__ csrc, const float* __restrict__ cnorm,
                                             int n, int mode) {
  int i = blockIdx.x * 256 + threadIdx.x;
  if (i >= n) return;
  float a0 = 0.f, a1 = 0.f;
  int e0 = offs[i], e1 = offs[i + 1];
  for (int e = e0; e < e1; ++e) {
    int s = csrc[e];
    float w = cnorm[e];
    a0 = fmaf(w, h[2 * s], a0);
    a1 = fmaf(w, h[2 * s + 1], a1);
  }
  if (mode) {
    a0 = 2.f * a0 - prev[2 * i];
    a1 = 2.f * a1 - prev[2 * i + 1];
  }
  out[2 * i] = a0;
  out[2 * i + 1] = a1;
}

// F=100 props: 2 nodes per 256-thread block, 128 threads (100 active) per node.
// mode=0: out = prop(h); mode=1: out = 2*prop(h) - prev  (prev may alias out: same-thread same-index RAW only)
__global__ __launch_bounds__(256) void prop_h(const float* __restrict__ h, const float* __restrict__ prev,
                                              float* __restrict__ out, const int* __restrict__ offs,
                                              const int* __restrict__ csrc, const float* __restrict__ cnorm,
                                              int n, int mode) {
  int node = blockIdx.x * 2 + (threadIdx.x >> 7);
  int f = threadIdx.x & 127;
  if (node >= n) return;
  float acc = 0.f;
  int e0 = offs[node], e1 = offs[node + 1];
  for (int e = e0; e < e1; ++e) {
    int s = csrc[e];
    float w = cnorm[e];
    // f up to 127 reads past the row; P0/P1 allocations are padded
    acc = fmaf(w, h[(size_t)s * H + f], acc);
  }
  if (f < H) {
    size_t o = (size_t)node * H + f;
    out[o] = (mode == 0) ? acc : (2.f * acc - prev[o]);
  }
}

// ---------------- GEMM: C (+)= A[N,100] @ W[100,100] (+bias if init) ----------------

__global__ __launch_bounds__(128) void gemm_acc(const float* __restrict__ A, const float* __restrict__ W,
                                                const float* __restrict__ bias, float* __restrict__ C,
                                                int n, int initMode) {
  __shared__ float WT[H][104];  // WT[f][c] = W[c][f]
  __shared__ float AT[32][104]; // AT[i][c]
  int t = threadIdx.x;
  for (int idx = t; idx < H * H; idx += 128) {
    int c = idx / H, f = idx - c * H;
    WT[f][c] = W[idx];
  }
  int n0 = blockIdx.x * 32;
  for (int idx = t; idx < 32 * H; idx += 128) {
    int i = idx / H, c = idx - i * H;
    AT[i][c] = A[(size_t)(n0 + i) * H + c];
  }
  __syncthreads();
  int f = t;
  bool act = f < H;
  int fr = act ? f : 0;
  float acc[32];
  if (act) {
    if (initMode) {
      float b = bias[f];
#pragma unroll
      for (int i = 0; i < 32; ++i) acc[i] = b;
    } else {
#pragma unroll
      for (int i = 0; i < 32; ++i) acc[i] = C[(size_t)(n0 + i) * H + f];
    }
  } else {
#pragma unroll
    for (int i = 0; i < 32; ++i) acc[i] = 0.f;
  }
  for (int c4 = 0; c4 < H / 4; ++c4) {
    float4 w = *(const float4*)&WT[fr][c4 * 4];
#pragma unroll
    for (int i = 0; i < 32; ++i) {
      float4 a = *(const float4*)&AT[i][c4 * 4];
      float s = acc[i];
      s = fmaf(a.x, w.x, s);
      s = fmaf(a.y, w.y, s);
      s = fmaf(a.z, w.z, s);
      s = fmaf(a.w, w.w, s);
      acc[i] = s;
    }
  }
  if (act) {
#pragma unroll
    for (int i = 0; i < 32; ++i) C[(size_t)(n0 + i) * H + f] = acc[i];
  }
}

// ---------------- layer 0 dense part: C = b0 + sum_{k,c} Tk[:,c] * W0[k,c,:] ----------------

__global__ __launch_bounds__(128) void layer0_out(const float* __restrict__ x, const float* __restrict__ t1,
                                                  const float* __restrict__ t2, const float* __restrict__ t3,
                                                  const float* __restrict__ t4, const float* __restrict__ W0,
                                                  const float* __restrict__ b0, float* __restrict__ C, int n) {
  int f = threadIdx.x;
  bool act = f < H;
  float w[10];
  float b = 0.f;
  if (act) {
#pragma unroll
    for (int j = 0; j < 10; ++j) w[j] = W0[j * H + f];
    b = b0[f];
  }
  int n0 = blockIdx.x * 32;
  int n1 = n0 + 32 < n ? n0 + 32 : n;
  for (int i = n0; i < n1; ++i) {
    if (!act) continue;
    float acc = b;
    acc = fmaf(x[2 * i],      w[0], acc);
    acc = fmaf(x[2 * i + 1],  w[1], acc);
    acc = fmaf(t1[2 * i],     w[2], acc);
    acc = fmaf(t1[2 * i + 1], w[3], acc);
    acc = fmaf(t2[2 * i],     w[4], acc);
    acc = fmaf(t2[2 * i + 1], w[5], acc);
    acc = fmaf(t3[2 * i],     w[6], acc);
    acc = fmaf(t3[2 * i + 1], w[7], acc);
    acc = fmaf(t4[2 * i],     w[8], acc);
    acc = fmaf(t4[2 * i + 1], w[9], acc);
    C[(size_t)i * H + f] = acc;
  }
}

// ---------------- batch norm ----------------

__global__ __launch_bounds__(128) void bn_stats(const float* __restrict__ acc, float* __restrict__ stats, int n) {
  int f = threadIdx.x;
  int n0 = blockIdx.x * 512;
  int n1 = n0 + 512 < n ? n0 + 512 : n;
  if (f < H) {
    float s = 0.f, s2 = 0.f;
    for (int i = n0; i < n1; ++i) {
      float v = fmaxf(acc[(size_t)i * H + f], 0.f);
      s += v;
      s2 = fmaf(v, v, s2);
    }
    atomicAdd(&stats[f], s);
    atomicAdd(&stats[128 + f], s2);
  }
}

__global__ __launch_bounds__(128) void bn_params(float* __restrict__ stats, const float* __restrict__ gamma,
                                                 const float* __restrict__ beta, int n) {
  int f = threadIdx.x;
  if (f >= H) return;
  float inv_n = 1.f / (float)n;
  float m = stats[f] * inv_n;
  float v = stats[128 + f] * inv_n - m * m;
  float is = rsqrtf(v + 1e-5f);
  float g = gamma[f] * is;
  stats[256 + f] = g;            // scale
  stats[384 + f] = beta[f] - m * g;  // shift
}

__global__ __launch_bounds__(256) void bn_final(const float* __restrict__ acc, const float* __restrict__ mi,
                                                float* __restrict__ out, int total) {
  int idx = blockIdx.x * 256 + threadIdx.x;
  if (idx >= total) return;
  int f = idx % H;
  float v = fmaxf(acc[idx], 0.f);
  out[idx] = fmaf(v, mi[f], mi[128 + f]);
}

// ---------------- launch ----------------

extern "C" void kernel_launch(void* const* d_in, const int* in_sizes, int n_in,
                              void* d_out, int out_size, void* d_ws, size_t ws_size,
                              hipStream_t stream) {
  const float* x     = (const float*)d_in[0];
  const int*   ei    = (const int*)d_in[1];
  const float* W0    = (const float*)d_in[2];
  const float* b0    = (const float*)d_in[3];
  const float* Wr    = (const float*)d_in[4];
  const float* br    = (const float*)d_in[5];
  const float* gamma = (const float*)d_in[6];
  const float* beta  = (const float*)d_in[7];
  float* C = (float*)d_out;

  const int N = in_sizes[0] / FIN;
  const int E = in_sizes[1] / 2;
  const int* src = ei;
  const int* dst = ei + E;

  char* ws = (char*)d_ws;
  size_t off = 0;
  auto alloc = [&](size_t bytes) -> void* {
    void* p = ws + off;
    off = (off + bytes + 255) & ~(size_t)255;
    return p;
  };

  size_t NB = (size_t)N * H * sizeof(float);
  float* P0       = (float*)alloc(NB + 1024);
  float* P1       = (float*)alloc(NB + 1024);
  float* t1       = (float*)alloc((size_t)N * 2 * 4);
  float* t2       = (float*)alloc((size_t)N * 2 * 4);
  float* t3       = (float*)alloc((size_t)N * 2 * 4);
  float* t4       = (float*)alloc((size_t)N * 2 * 4);
  float* deg      = (float*)alloc((size_t)N * 4);
  int*   indeg    = (int*)alloc((size_t)N * 4);
  float* dinv     = (float*)alloc((size_t)N * 4);
  int*   incl     = (int*)alloc((size_t)N * 4);
  int*   bsum     = (int*)alloc(8192 * 4);
  int*   bscan    = (int*)alloc(8192 * 4);
  int*   offsets  = (int*)alloc((size_t)(N + 1) * 4);
  int*   cursor   = (int*)alloc((size_t)N * 4);
  int*   csr_src  = (int*)alloc((size_t)E * 4);
  float* csr_norm = (float*)alloc((size_t)E * 4);
  float* stats    = (float*)alloc(512 * 4);

  int gE = (E + 255) / 256;
  int gN = (N + 255) / 256;

  hipMemsetAsync(deg, 0, (size_t)N * 4, stream);
  hipMemsetAsync(indeg, 0, (size_t)N * 4, stream);

  deg_kernel<<<gE, 256, 0, stream>>>(src, dst, deg, indeg, E);
  dinv_kernel<<<gN, 256, 0, stream>>>(deg, dinv, N);
  scan_block<<<gN, 256, 0, stream>>>(indeg, incl, bsum, N);
  scan_sums<<<1, 256, 0, stream>>>(bsum, bscan, gN);
  finalize_offsets<<<gN, 256, 0, stream>>>(incl, indeg, bscan, offsets, cursor, N, E);
  build_csr<<<gE, 256, 0, stream>>>(src, dst, dinv, cursor, csr_src, csr_norm, E);

  // ---- layer 0 (F_IN = 2) ----
  prop2<<<gN, 256, 0, stream>>>(x,  x,  t1, offsets, csr_src, csr_norm, N, 0);
  prop2<<<gN, 256, 0, stream>>>(t1, x,  t2, offsets, csr_src, csr_norm, N, 1);
  prop2<<<gN, 256, 0, stream>>>(t2, t1, t3, offsets, csr_src, csr_norm, N, 1);
  prop2<<<gN, 256, 0, stream>>>(t3, t2, t4, offsets, csr_src, csr_norm, N, 1);
  layer0_out<<<(N + 31) / 32, 128, 0, stream>>>(x, t1, t2, t3, t4, W0, b0, C, N);
  hipMemsetAsync(stats, 0, 1024, stream);
  bn_stats<<<(N + 511) / 512, 128, 0, stream>>>(C, stats, N);
  bn_params<<<1, 128, 0, stream>>>(stats, gamma, beta, N);
  bn_final<<<(N * H + 255) / 256, 256, 0, stream>>>(C, stats + 256, P0, N * H);

  // ---- layers 1..4 (H = 100) ----
  int gG = (N + 31) / 32;
  int gP = (N + 1) / 2;
  for (int layer = 1; layer < 5; ++layer) {
    const float* Wl = Wr + (size_t)(layer - 1) * KORD * H * H;
    const float* bl = br + (size_t)(layer - 1) * H;
    // T0 = h (P0). acc = T0 @ W[0] + b
    gemm_acc<<<gG, 128, 0, stream>>>(P0, Wl, bl, C, N, 1);
    // T1 = prop(T0) -> P1 ; acc += T1 @ W[1]
    prop_h<<<gP, 256, 0, stream>>>(P0, P0, P1, offsets, csr_src, csr_norm, N, 0);
    gemm_acc<<<gG, 128, 0, stream>>>(P1, Wl + 1 * H * H, bl, C, N, 0);
    // T2 = 2*prop(T1) - T0 -> P0 (in place over T0)
    prop_h<<<gP, 256, 0, stream>>>(P1, P0, P0, offsets, csr_src, csr_norm, N, 1);
    gemm_acc<<<gG, 128, 0, stream>>>(P0, Wl + 2 * H * H, bl, C, N, 0);
    // T3 = 2*prop(T2) - T1 -> P1
    prop_h<<<gP, 256, 0, stream>>>(P0, P1, P1, offsets, csr_src, csr_norm, N, 1);
    gemm_acc<<<gG, 128, 0, stream>>>(P1, Wl + 3 * H * H, bl, C, N, 0);
    // T4 = 2*prop(T3) - T2 -> P0
    prop_h<<<gP, 256, 0, stream>>>(P1, P0, P0, offsets, csr_src, csr_norm, N, 1);
    gemm_acc<<<gG, 128, 0, stream>>>(P0, Wl + 4 * H * H, bl, C, N, 0);
    // BN(relu(acc)) -> next h (P0), or d_out for last layer
    hipMemsetAsync(stats, 0, 1024, stream);
    bn_stats<<<(N + 511) / 512, 128, 0, stream>>>(C, stats, N);
    bn_params<<<1, 128, 0, stream>>>(stats, gamma + (size_t)layer * H, beta + (size_t)layer * H, N);
    bn_final<<<(N * H + 255) / 256, 256, 0, stream>>>(C, stats + 256, (layer < 4) ? P0 : C, N * H);
  }
}

// Round 3
// 18977.313 us; speedup vs baseline: 1.2410x; 1.2410x over previous
//
#include <hip/hip_runtime.h>

#define H 100
#define FIN 2
#define KORD 5

// ---------------- graph setup ----------------

__global__ __launch_bounds__(256) void deg_kernel(const int* __restrict__ src, const int* __restrict__ dst,
                                                  float* __restrict__ deg, int* __restrict__ indeg, int E) {
  int e = blockIdx.x * 256 + threadIdx.x;
  if (e < E) {
    atomicAdd(&deg[src[e]], 1.0f);
    atomicAdd(&indeg[dst[e]], 1);
  }
}

__global__ __launch_bounds__(256) void dinv_kernel(const float* __restrict__ deg, float* __restrict__ dinv, int n) {
  int i = blockIdx.x * 256 + threadIdx.x;
  if (i < n) {
    float d = deg[i];
    dinv[i] = d > 0.f ? rsqrtf(fmaxf(d, 1.f)) : 0.f;
  }
}

__global__ __launch_bounds__(256) void scan_block(const int* __restrict__ in, int* __restrict__ incl,
                                                  int* __restrict__ bsum, int n) {
  __shared__ int s[256];
  int i = blockIdx.x * 256 + threadIdx.x;
  int v = (i < n) ? in[i] : 0;
  s[threadIdx.x] = v;
  __syncthreads();
  for (int d = 1; d < 256; d <<= 1) {
    int t = (threadIdx.x >= d) ? s[threadIdx.x - d] : 0;
    __syncthreads();
    s[threadIdx.x] += t;
    __syncthreads();
  }
  if (i < n) incl[i] = s[threadIdx.x];
  if (threadIdx.x == 255) bsum[blockIdx.x] = s[255];
}

__global__ __launch_bounds__(256) void scan_sums(const int* __restrict__ bsum, int* __restrict__ bscan, int nb) {
  __shared__ int s[256];
  __shared__ int carry;
  if (threadIdx.x == 0) carry = 0;
  __syncthreads();
  for (int base = 0; base < nb; base += 256) {
    int i = base + threadIdx.x;
    int v = (i < nb) ? bsum[i] : 0;
    s[threadIdx.x] = v;
    __syncthreads();
    for (int d = 1; d < 256; d <<= 1) {
      int t = (threadIdx.x >= d) ? s[threadIdx.x - d] : 0;
      __syncthreads();
      s[threadIdx.x] += t;
      __syncthreads();
    }
    int c = carry;
    if (i < nb) bscan[i] = s[threadIdx.x] + c;
    __syncthreads();
    if (threadIdx.x == 0) carry = c + s[255];
    __syncthreads();
  }
}

__global__ __launch_bounds__(256) void finalize_offsets(const int* __restrict__ incl, const int* __restrict__ indeg,
                                                        const int* __restrict__ bscan, int* __restrict__ offsets,
                                                        int* __restrict__ cursor, int n, int total) {
  int i = blockIdx.x * 256 + threadIdx.x;
  if (i < n) {
    int prev = (blockIdx.x > 0) ? bscan[blockIdx.x - 1] : 0;
    int excl = incl[i] - indeg[i] + prev;
    offsets[i] = excl;
    cursor[i] = excl;
  }
  if (i == 0) offsets[n] = total;
}

__global__ __launch_bounds__(256) void build_csr(const int* __restrict__ src, const int* __restrict__ dst,
                                                 const float* __restrict__ dinv, int* __restrict__ cursor,
                                                 int* __restrict__ csr_src, float* __restrict__ csr_norm, int E) {
  int e = blockIdx.x * 256 + threadIdx.x;
  if (e < E) {
    int s = src[e], d = dst[e];
    float nrm = -dinv[s] * dinv[d];
    int p = atomicAdd(&cursor[d], 1);
    csr_src[p] = s;
    csr_norm[p] = nrm;
  }
}

// ---------------- propagate ----------------

// F=2 props for layer 0 (thread per node), 4x unrolled edge loop for MLP
__global__ __launch_bounds__(256) void prop2(const float* __restrict__ h, const float* __restrict__ prev,
                                             float* __restrict__ out, const int* __restrict__ offs,
                                             const int* __restrict__ csrc, const float* __restrict__ cnorm,
                                             int n, int mode) {
  int i = blockIdx.x * 256 + threadIdx.x;
  if (i >= n) return;
  float a0 = 0.f, a1 = 0.f;
  int e0 = offs[i], e1 = offs[i + 1];
  int e = e0;
  for (; e + 4 <= e1; e += 4) {
    int s0 = csrc[e], s1 = csrc[e + 1], s2 = csrc[e + 2], s3 = csrc[e + 3];
    float w0 = cnorm[e], w1 = cnorm[e + 1], w2 = cnorm[e + 2], w3 = cnorm[e + 3];
    float x0 = h[2 * s0], y0 = h[2 * s0 + 1];
    float x1 = h[2 * s1], y1 = h[2 * s1 + 1];
    float x2 = h[2 * s2], y2 = h[2 * s2 + 1];
    float x3 = h[2 * s3], y3 = h[2 * s3 + 1];
    a0 = fmaf(w0, x0, a0); a1 = fmaf(w0, y0, a1);
    a0 = fmaf(w1, x1, a0); a1 = fmaf(w1, y1, a1);
    a0 = fmaf(w2, x2, a0); a1 = fmaf(w2, y2, a1);
    a0 = fmaf(w3, x3, a0); a1 = fmaf(w3, y3, a1);
  }
  for (; e < e1; ++e) {
    int s = csrc[e];
    float w = cnorm[e];
    a0 = fmaf(w, h[2 * s], a0);
    a1 = fmaf(w, h[2 * s + 1], a1);
  }
  if (mode) {
    a0 = 2.f * a0 - prev[2 * i];
    a1 = 2.f * a1 - prev[2 * i + 1];
  }
  out[2 * i] = a0;
  out[2 * i + 1] = a1;
}

// F=100 props: 2 nodes per 256-thread block, 128 threads (100 active) per node.
// 4x unrolled edge loop: 4 independent (src,norm) loads then 4 independent gathers -> MLP~4.
// mode=0: out = prop(h); mode=1: out = 2*prop(h) - prev (prev may alias out: same-thread RAW only)
__global__ __launch_bounds__(256) void prop_h(const float* __restrict__ h, const float* __restrict__ prev,
                                              float* __restrict__ out, const int* __restrict__ offs,
                                              const int* __restrict__ csrc, const float* __restrict__ cnorm,
                                              int n, int mode) {
  int node = blockIdx.x * 2 + (threadIdx.x >> 7);
  int f = threadIdx.x & 127;
  if (node >= n) return;
  float acc = 0.f;
  int e0 = offs[node], e1 = offs[node + 1];
  int e = e0;
  for (; e + 4 <= e1; e += 4) {
    int s0 = csrc[e], s1 = csrc[e + 1], s2 = csrc[e + 2], s3 = csrc[e + 3];
    float w0 = cnorm[e], w1 = cnorm[e + 1], w2 = cnorm[e + 2], w3 = cnorm[e + 3];
    // f up to 127 reads past the row end; P0/P1 allocations are padded
    float v0 = h[(size_t)s0 * H + f];
    float v1 = h[(size_t)s1 * H + f];
    float v2 = h[(size_t)s2 * H + f];
    float v3 = h[(size_t)s3 * H + f];
    acc = fmaf(w0, v0, acc);
    acc = fmaf(w1, v1, acc);
    acc = fmaf(w2, v2, acc);
    acc = fmaf(w3, v3, acc);
  }
  for (; e < e1; ++e) {
    int s = csrc[e];
    float w = cnorm[e];
    acc = fmaf(w, h[(size_t)s * H + f], acc);
  }
  if (f < H) {
    size_t o = (size_t)node * H + f;
    out[o] = (mode == 0) ? acc : (2.f * acc - prev[o]);
  }
}

// ---------------- GEMM: C (+)= A[N,100] @ W[100,100] (+bias if init) ----------------
// R0-proven version (LDS-staged W^T and A-tile, 32 rows/block, 128 threads).

__global__ __launch_bounds__(128) void gemm_acc(const float* __restrict__ A, const float* __restrict__ W,
                                                const float* __restrict__ bias, float* __restrict__ C,
                                                int n, int initMode) {
  __shared__ float WT[H][104];  // WT[f][c] = W[c][f]
  __shared__ float AT[32][104]; // AT[i][c]
  int t = threadIdx.x;
  for (int idx = t; idx < H * H; idx += 128) {
    int c = idx / H, f = idx - c * H;
    WT[f][c] = W[idx];
  }
  int n0 = blockIdx.x * 32;
  for (int idx = t; idx < 32 * H; idx += 128) {
    int i = idx / H, c = idx - i * H;
    AT[i][c] = A[(size_t)(n0 + i) * H + c];
  }
  __syncthreads();
  int f = t;
  bool act = f < H;
  int fr = act ? f : 0;
  float acc[32];
  if (act) {
    if (initMode) {
      float b = bias[f];
#pragma unroll
      for (int i = 0; i < 32; ++i) acc[i] = b;
    } else {
#pragma unroll
      for (int i = 0; i < 32; ++i) acc[i] = C[(size_t)(n0 + i) * H + f];
    }
  } else {
#pragma unroll
    for (int i = 0; i < 32; ++i) acc[i] = 0.f;
  }
  for (int c4 = 0; c4 < H / 4; ++c4) {
    float4 w = *(const float4*)&WT[fr][c4 * 4];
#pragma unroll
    for (int i = 0; i < 32; ++i) {
      float4 a = *(const float4*)&AT[i][c4 * 4];
      float s = acc[i];
      s = fmaf(a.x, w.x, s);
      s = fmaf(a.y, w.y, s);
      s = fmaf(a.z, w.z, s);
      s = fmaf(a.w, w.w, s);
      acc[i] = s;
    }
  }
  if (act) {
#pragma unroll
    for (int i = 0; i < 32; ++i) C[(size_t)(n0 + i) * H + f] = acc[i];
  }
}

// ---------------- layer 0 dense part: C = b0 + sum_{k,c} Tk[:,c] * W0[k,c,:] ----------------

__global__ __launch_bounds__(128) void layer0_out(const float* __restrict__ x, const float* __restrict__ t1,
                                                  const float* __restrict__ t2, const float* __restrict__ t3,
                                                  const float* __restrict__ t4, const float* __restrict__ W0,
                                                  const float* __restrict__ b0, float* __restrict__ C, int n) {
  int f = threadIdx.x;
  bool act = f < H;
  float w[10];
  float b = 0.f;
  if (act) {
#pragma unroll
    for (int j = 0; j < 10; ++j) w[j] = W0[j * H + f];
    b = b0[f];
  }
  int n0 = blockIdx.x * 32;
  int n1 = n0 + 32 < n ? n0 + 32 : n;
  for (int i = n0; i < n1; ++i) {
    if (!act) continue;
    float acc = b;
    acc = fmaf(x[2 * i],      w[0], acc);
    acc = fmaf(x[2 * i + 1],  w[1], acc);
    acc = fmaf(t1[2 * i],     w[2], acc);
    acc = fmaf(t1[2 * i + 1], w[3], acc);
    acc = fmaf(t2[2 * i],     w[4], acc);
    acc = fmaf(t2[2 * i + 1], w[5], acc);
    acc = fmaf(t3[2 * i],     w[6], acc);
    acc = fmaf(t3[2 * i + 1], w[7], acc);
    acc = fmaf(t4[2 * i],     w[8], acc);
    acc = fmaf(t4[2 * i + 1], w[9], acc);
    C[(size_t)i * H + f] = acc;
  }
}

// ---------------- batch norm ----------------

__global__ __launch_bounds__(128) void bn_stats(const float* __restrict__ acc, float* __restrict__ stats, int n) {
  int f = threadIdx.x;
  int n0 = blockIdx.x * 512;
  int n1 = n0 + 512 < n ? n0 + 512 : n;
  if (f < H) {
    float s = 0.f, s2 = 0.f;
    for (int i = n0; i < n1; ++i) {
      float v = fmaxf(acc[(size_t)i * H + f], 0.f);
      s += v;
      s2 = fmaf(v, v, s2);
    }
    atomicAdd(&stats[f], s);
    atomicAdd(&stats[128 + f], s2);
  }
}

__global__ __launch_bounds__(128) void bn_params(float* __restrict__ stats, const float* __restrict__ gamma,
                                                 const float* __restrict__ beta, int n) {
  int f = threadIdx.x;
  if (f >= H) return;
  float inv_n = 1.f / (float)n;
  float m = stats[f] * inv_n;
  float v = stats[128 + f] * inv_n - m * m;
  float is = rsqrtf(v + 1e-5f);
  float g = gamma[f] * is;
  stats[256 + f] = g;                // scale
  stats[384 + f] = beta[f] - m * g;  // shift
}

__global__ __launch_bounds__(256) void bn_final(const float* __restrict__ acc, const float* __restrict__ mi,
                                                float* __restrict__ out, int total) {
  int idx = blockIdx.x * 256 + threadIdx.x;
  if (idx >= total) return;
  int f = idx % H;
  float v = fmaxf(acc[idx], 0.f);
  out[idx] = fmaf(v, mi[f], mi[128 + f]);
}

// ---------------- launch ----------------

extern "C" void kernel_launch(void* const* d_in, const int* in_sizes, int n_in,
                              void* d_out, int out_size, void* d_ws, size_t ws_size,
                              hipStream_t stream) {
  const float* x     = (const float*)d_in[0];
  const int*   ei    = (const int*)d_in[1];
  const float* W0    = (const float*)d_in[2];
  const float* b0    = (const float*)d_in[3];
  const float* Wr    = (const float*)d_in[4];
  const float* br    = (const float*)d_in[5];
  const float* gamma = (const float*)d_in[6];
  const float* beta  = (const float*)d_in[7];
  float* C = (float*)d_out;

  const int N = in_sizes[0] / FIN;
  const int E = in_sizes[1] / 2;
  const int* src = ei;
  const int* dst = ei + E;

  char* ws = (char*)d_ws;
  size_t off = 0;
  auto alloc = [&](size_t bytes) -> void* {
    void* p = ws + off;
    off = (off + bytes + 255) & ~(size_t)255;
    return p;
  };

  size_t NB = (size_t)N * H * sizeof(float);
  float* P0       = (float*)alloc(NB + 1024);
  float* P1       = (float*)alloc(NB + 1024);
  float* t1       = (float*)alloc((size_t)N * 2 * 4);
  float* t2       = (float*)alloc((size_t)N * 2 * 4);
  float* t3       = (float*)alloc((size_t)N * 2 * 4);
  float* t4       = (float*)alloc((size_t)N * 2 * 4);
  float* deg      = (float*)alloc((size_t)N * 4);
  int*   indeg    = (int*)alloc((size_t)N * 4);
  float* dinv     = (float*)alloc((size_t)N * 4);
  int*   incl     = (int*)alloc((size_t)N * 4);
  int*   bsum     = (int*)alloc(8192 * 4);
  int*   bscan    = (int*)alloc(8192 * 4);
  int*   offsets  = (int*)alloc((size_t)(N + 1) * 4);
  int*   cursor   = (int*)alloc((size_t)N * 4);
  int*   csr_src  = (int*)alloc((size_t)E * 4);
  float* csr_norm = (float*)alloc((size_t)E * 4);
  float* stats    = (float*)alloc(512 * 4);

  int gE = (E + 255) / 256;
  int gN = (N + 255) / 256;

  hipMemsetAsync(deg, 0, (size_t)N * 4, stream);
  hipMemsetAsync(indeg, 0, (size_t)N * 4, stream);

  deg_kernel<<<gE, 256, 0, stream>>>(src, dst, deg, indeg, E);
  dinv_kernel<<<gN, 256, 0, stream>>>(deg, dinv, N);
  scan_block<<<gN, 256, 0, stream>>>(indeg, incl, bsum, N);
  scan_sums<<<1, 256, 0, stream>>>(bsum, bscan, gN);
  finalize_offsets<<<gN, 256, 0, stream>>>(incl, indeg, bscan, offsets, cursor, N, E);
  build_csr<<<gE, 256, 0, stream>>>(src, dst, dinv, cursor, csr_src, csr_norm, E);

  // ---- layer 0 (F_IN = 2) ----
  prop2<<<gN, 256, 0, stream>>>(x,  x,  t1, offsets, csr_src, csr_norm, N, 0);
  prop2<<<gN, 256, 0, stream>>>(t1, x,  t2, offsets, csr_src, csr_norm, N, 1);
  prop2<<<gN, 256, 0, stream>>>(t2, t1, t3, offsets, csr_src, csr_norm, N, 1);
  prop2<<<gN, 256, 0, stream>>>(t3, t2, t4, offsets, csr_src, csr_norm, N, 1);
  layer0_out<<<(N + 31) / 32, 128, 0, stream>>>(x, t1, t2, t3, t4, W0, b0, C, N);
  hipMemsetAsync(stats, 0, 1024, stream);
  bn_stats<<<(N + 511) / 512, 128, 0, stream>>>(C, stats, N);
  bn_params<<<1, 128, 0, stream>>>(stats, gamma, beta, N);
  bn_final<<<(N * H + 255) / 256, 256, 0, stream>>>(C, stats + 256, P0, N * H);

  // ---- layers 1..4 (H = 100) ----
  int gG = (N + 31) / 32;
  int gP = (N + 1) / 2;
  for (int layer = 1; layer < 5; ++layer) {
    const float* Wl = Wr + (size_t)(layer - 1) * KORD * H * H;
    const float* bl = br + (size_t)(layer - 1) * H;
    // T0 = h (P0). acc = T0 @ W[0] + b
    gemm_acc<<<gG, 128, 0, stream>>>(P0, Wl, bl, C, N, 1);
    // T1 = prop(T0) -> P1 ; acc += T1 @ W[1]
    prop_h<<<gP, 256, 0, stream>>>(P0, P0, P1, offsets, csr_src, csr_norm, N, 0);
    gemm_acc<<<gG, 128, 0, stream>>>(P1, Wl + 1 * H * H, bl, C, N, 0);
    // T2 = 2*prop(T1) - T0 -> P0 (in place over T0)
    prop_h<<<gP, 256, 0, stream>>>(P1, P0, P0, offsets, csr_src, csr_norm, N, 1);
    gemm_acc<<<gG, 128, 0, stream>>>(P0, Wl + 2 * H * H, bl, C, N, 0);
    // T3 = 2*prop(T2) - T1 -> P1
    prop_h<<<gP, 256, 0, stream>>>(P0, P1, P1, offsets, csr_src, csr_norm, N, 1);
    gemm_acc<<<gG, 128, 0, stream>>>(P1, Wl + 3 * H * H, bl, C, N, 0);
    // T4 = 2*prop(T3) - T2 -> P0
    prop_h<<<gP, 256, 0, stream>>>(P1, P0, P0, offsets, csr_src, csr_norm, N, 1);
    gemm_acc<<<gG, 128, 0, stream>>>(P0, Wl + 4 * H * H, bl, C, N, 0);
    // BN(relu(acc)) -> next h (P0), or d_out for last layer
    hipMemsetAsync(stats, 0, 1024, stream);
    bn_stats<<<(N + 511) / 512, 128, 0, stream>>>(C, stats, N);
    bn_params<<<1, 128, 0, stream>>>(stats, gamma + (size_t)layer * H, beta + (size_t)layer * H, N);
    bn_final<<<(N * H + 255) / 256, 256, 0, stream>>>(C, stats + 256, (layer < 4) ? P0 : C, N * H);
  }
}

// Round 4
// 12158.824 us; speedup vs baseline: 1.9370x; 1.5608x over previous
//
#include <hip/hip_runtime.h>

#define H 100
#define FIN 2
#define KORD 5

// ---------------- graph setup ----------------

__global__ __launch_bounds__(256) void deg_kernel(const int* __restrict__ src, const int* __restrict__ dst,
                                                  float* __restrict__ deg, int* __restrict__ indeg, int E) {
  int e = blockIdx.x * 256 + threadIdx.x;
  if (e < E) {
    atomicAdd(&deg[src[e]], 1.0f);
    atomicAdd(&indeg[dst[e]], 1);
  }
}

__global__ __launch_bounds__(256) void dinv_kernel(const float* __restrict__ deg, float* __restrict__ dinv, int n) {
  int i = blockIdx.x * 256 + threadIdx.x;
  if (i < n) {
    float d = deg[i];
    dinv[i] = d > 0.f ? rsqrtf(fmaxf(d, 1.f)) : 0.f;
  }
}

__global__ __launch_bounds__(256) void scan_block(const int* __restrict__ in, int* __restrict__ incl,
                                                  int* __restrict__ bsum, int n) {
  __shared__ int s[256];
  int i = blockIdx.x * 256 + threadIdx.x;
  int v = (i < n) ? in[i] : 0;
  s[threadIdx.x] = v;
  __syncthreads();
  for (int d = 1; d < 256; d <<= 1) {
    int t = (threadIdx.x >= d) ? s[threadIdx.x - d] : 0;
    __syncthreads();
    s[threadIdx.x] += t;
    __syncthreads();
  }
  if (i < n) incl[i] = s[threadIdx.x];
  if (threadIdx.x == 255) bsum[blockIdx.x] = s[255];
}

__global__ __launch_bounds__(256) void scan_sums(const int* __restrict__ bsum, int* __restrict__ bscan, int nb) {
  __shared__ int s[256];
  __shared__ int carry;
  if (threadIdx.x == 0) carry = 0;
  __syncthreads();
  for (int base = 0; base < nb; base += 256) {
    int i = base + threadIdx.x;
    int v = (i < nb) ? bsum[i] : 0;
    s[threadIdx.x] = v;
    __syncthreads();
    for (int d = 1; d < 256; d <<= 1) {
      int t = (threadIdx.x >= d) ? s[threadIdx.x - d] : 0;
      __syncthreads();
      s[threadIdx.x] += t;
      __syncthreads();
    }
    int c = carry;
    if (i < nb) bscan[i] = s[threadIdx.x] + c;
    __syncthreads();
    if (threadIdx.x == 0) carry = c + s[255];
    __syncthreads();
  }
}

__global__ __launch_bounds__(256) void finalize_offsets(const int* __restrict__ incl, const int* __restrict__ indeg,
                                                        const int* __restrict__ bscan, int* __restrict__ offsets,
                                                        int* __restrict__ cursor, int n, int total) {
  int i = blockIdx.x * 256 + threadIdx.x;
  if (i < n) {
    int prev = (blockIdx.x > 0) ? bscan[blockIdx.x - 1] : 0;
    int excl = incl[i] - indeg[i] + prev;
    offsets[i] = excl;
    cursor[i] = excl;
  }
  if (i == 0) offsets[n] = total;
}

__global__ __launch_bounds__(256) void build_csr(const int* __restrict__ src, const int* __restrict__ dst,
                                                 const float* __restrict__ dinv, int* __restrict__ cursor,
                                                 int* __restrict__ csr_src, float* __restrict__ csr_norm, int E) {
  int e = blockIdx.x * 256 + threadIdx.x;
  if (e < E) {
    int s = src[e], d = dst[e];
    float nrm = -dinv[s] * dinv[d];
    int p = atomicAdd(&cursor[d], 1);
    csr_src[p] = s;
    csr_norm[p] = nrm;
  }
}

// ---------------- propagate ----------------

// F=2 props for layer 0 (thread per node), 4x unrolled edge loop for MLP
__global__ __launch_bounds__(256) void prop2(const float* __restrict__ h, const float* __restrict__ prev,
                                             float* __restrict__ out, const int* __restrict__ offs,
                                             const int* __restrict__ csrc, const float* __restrict__ cnorm,
                                             int n, int mode) {
  int i = blockIdx.x * 256 + threadIdx.x;
  if (i >= n) return;
  float a0 = 0.f, a1 = 0.f;
  int e0 = offs[i], e1 = offs[i + 1];
  int e = e0;
  for (; e + 4 <= e1; e += 4) {
    int s0 = csrc[e], s1 = csrc[e + 1], s2 = csrc[e + 2], s3 = csrc[e + 3];
    float w0 = cnorm[e], w1 = cnorm[e + 1], w2 = cnorm[e + 2], w3 = cnorm[e + 3];
    float x0 = h[2 * s0], y0 = h[2 * s0 + 1];
    float x1 = h[2 * s1], y1 = h[2 * s1 + 1];
    float x2 = h[2 * s2], y2 = h[2 * s2 + 1];
    float x3 = h[2 * s3], y3 = h[2 * s3 + 1];
    a0 = fmaf(w0, x0, a0); a1 = fmaf(w0, y0, a1);
    a0 = fmaf(w1, x1, a0); a1 = fmaf(w1, y1, a1);
    a0 = fmaf(w2, x2, a0); a1 = fmaf(w2, y2, a1);
    a0 = fmaf(w3, x3, a0); a1 = fmaf(w3, y3, a1);
  }
  for (; e < e1; ++e) {
    int s = csrc[e];
    float w = cnorm[e];
    a0 = fmaf(w, h[2 * s], a0);
    a1 = fmaf(w, h[2 * s + 1], a1);
  }
  if (mode) {
    a0 = 2.f * a0 - prev[2 * i];
    a1 = 2.f * a1 - prev[2 * i + 1];
  }
  out[2 * i] = a0;
  out[2 * i + 1] = a1;
}

// F=100 props: 2 nodes per 256-thread block, 128 threads (100 active) per node.
// 4x unrolled edge loop: 4 independent (src,norm) loads then 4 independent gathers -> MLP~4.
__global__ __launch_bounds__(256) void prop_h(const float* __restrict__ h, const float* __restrict__ prev,
                                              float* __restrict__ out, const int* __restrict__ offs,
                                              const int* __restrict__ csrc, const float* __restrict__ cnorm,
                                              int n, int mode) {
  int node = blockIdx.x * 2 + (threadIdx.x >> 7);
  int f = threadIdx.x & 127;
  if (node >= n) return;
  float acc = 0.f;
  int e0 = offs[node], e1 = offs[node + 1];
  int e = e0;
  for (; e + 4 <= e1; e += 4) {
    int s0 = csrc[e], s1 = csrc[e + 1], s2 = csrc[e + 2], s3 = csrc[e + 3];
    float w0 = cnorm[e], w1 = cnorm[e + 1], w2 = cnorm[e + 2], w3 = cnorm[e + 3];
    // f up to 127 reads past the row end; T buffers are padded
    float v0 = h[(size_t)s0 * H + f];
    float v1 = h[(size_t)s1 * H + f];
    float v2 = h[(size_t)s2 * H + f];
    float v3 = h[(size_t)s3 * H + f];
    acc = fmaf(w0, v0, acc);
    acc = fmaf(w1, v1, acc);
    acc = fmaf(w2, v2, acc);
    acc = fmaf(w3, v3, acc);
  }
  for (; e < e1; ++e) {
    int s = csrc[e];
    float w = cnorm[e];
    acc = fmaf(w, h[(size_t)s * H + f], acc);
  }
  if (f < H) {
    size_t o = (size_t)node * H + f;
    out[o] = (mode == 0) ? acc : (2.f * acc - prev[o]);
  }
}

// ---------------- fused-k GEMM ----------------
// C[row,f] = init + sum_{k<nk} sum_c Tk[row,c] * W[k*H*H + c*H + f]
// init = bias[f] (initMode=1, pure write) or C[row,f] (initMode=0, RMW once).
// 256 threads: row i = t&63 (64-row tile), col strip fb = 25*(t>>6).
// A tile in LDS [64][101] (25.9 KB, odd stride -> conflict-free); accumulator in
// registers across all k (kills the per-k C RMW of the old design); W read via
// wave-uniform addresses -> scalar s_load pipe (no LDS, no VGPR W traffic).

__global__ __launch_bounds__(256) void gemm_multi(const float* __restrict__ Ta, const float* __restrict__ Tb,
                                                  const float* __restrict__ Tc, int nk,
                                                  const float* __restrict__ W, const float* __restrict__ bias,
                                                  float* __restrict__ C, int n, int initMode) {
  __shared__ float AT[64][101];
  int t = threadIdx.x;
  int i = t & 63;
  int g = (int)__builtin_amdgcn_readfirstlane((unsigned)(t >> 6));
  int fb = 25 * g;
  int n0 = blockIdx.x * 64;
  int row = n0 + i;
  bool act = row < n;

  float acc[25];
  if (initMode) {
    const float* bp = bias + fb;  // uniform -> s_load
#pragma unroll
    for (int j = 0; j < 25; ++j) acc[j] = bp[j];
  } else {
    const float* Cp = C + (size_t)row * H + fb;
#pragma unroll
    for (int j = 0; j < 25; ++j) acc[j] = act ? Cp[j] : 0.f;
  }

  for (int k = 0; k < nk; ++k) {
    const float* Tk = (k == 0) ? Ta : ((k == 1) ? Tb : Tc);
    __syncthreads();  // protect AT reuse from previous k
    for (int idx = t; idx < 64 * H; idx += 256) {
      int r = idx / H, c = idx - r * H;
      int rr = n0 + r;
      AT[r][c] = (rr < n) ? Tk[(size_t)rr * H + c] : 0.f;
    }
    __syncthreads();
    const float* Wk = W + (size_t)k * H * H + fb;  // uniform
#pragma unroll 4
    for (int c = 0; c < H; ++c) {
      float a = AT[i][c];
      const float* Wc = Wk + c * H;  // uniform -> s_load_dwordx*
#pragma unroll
      for (int j = 0; j < 25; ++j) acc[j] = fmaf(a, Wc[j], acc[j]);
    }
  }

  if (act) {
    float* Cp = C + (size_t)row * H + fb;
#pragma unroll
    for (int j = 0; j < 25; ++j) Cp[j] = acc[j];
  }
}

// ---------------- layer 0 dense part: C = b0 + sum_{k,c} Tk[:,c] * W0[k,c,:] ----------------

__global__ __launch_bounds__(128) void layer0_out(const float* __restrict__ x, const float* __restrict__ t1,
                                                  const float* __restrict__ t2, const float* __restrict__ t3,
                                                  const float* __restrict__ t4, const float* __restrict__ W0,
                                                  const float* __restrict__ b0, float* __restrict__ C, int n) {
  int f = threadIdx.x;
  bool act = f < H;
  float w[10];
  float b = 0.f;
  if (act) {
#pragma unroll
    for (int j = 0; j < 10; ++j) w[j] = W0[j * H + f];
    b = b0[f];
  }
  int n0 = blockIdx.x * 32;
  int n1 = n0 + 32 < n ? n0 + 32 : n;
  for (int i = n0; i < n1; ++i) {
    if (!act) continue;
    float acc = b;
    acc = fmaf(x[2 * i],      w[0], acc);
    acc = fmaf(x[2 * i + 1],  w[1], acc);
    acc = fmaf(t1[2 * i],     w[2], acc);
    acc = fmaf(t1[2 * i + 1], w[3], acc);
    acc = fmaf(t2[2 * i],     w[4], acc);
    acc = fmaf(t2[2 * i + 1], w[5], acc);
    acc = fmaf(t3[2 * i],     w[6], acc);
    acc = fmaf(t3[2 * i + 1], w[7], acc);
    acc = fmaf(t4[2 * i],     w[8], acc);
    acc = fmaf(t4[2 * i + 1], w[9], acc);
    C[(size_t)i * H + f] = acc;
  }
}

// ---------------- batch norm ----------------

__global__ __launch_bounds__(128) void bn_stats(const float* __restrict__ acc, float* __restrict__ stats, int n) {
  int f = threadIdx.x;
  int n0 = blockIdx.x * 512;
  int n1 = n0 + 512 < n ? n0 + 512 : n;
  if (f < H) {
    float s = 0.f, s2 = 0.f;
    for (int i = n0; i < n1; ++i) {
      float v = fmaxf(acc[(size_t)i * H + f], 0.f);
      s += v;
      s2 = fmaf(v, v, s2);
    }
    atomicAdd(&stats[f], s);
    atomicAdd(&stats[128 + f], s2);
  }
}

__global__ __launch_bounds__(128) void bn_params(float* __restrict__ stats, const float* __restrict__ gamma,
                                                 const float* __restrict__ beta, int n) {
  int f = threadIdx.x;
  if (f >= H) return;
  float inv_n = 1.f / (float)n;
  float m = stats[f] * inv_n;
  float v = stats[128 + f] * inv_n - m * m;
  float is = rsqrtf(v + 1e-5f);
  float g = gamma[f] * is;
  stats[256 + f] = g;                // scale
  stats[384 + f] = beta[f] - m * g;  // shift
}

__global__ __launch_bounds__(256) void bn_final(const float* __restrict__ acc, const float* __restrict__ mi,
                                                float* __restrict__ out, int total) {
  int idx = blockIdx.x * 256 + threadIdx.x;
  if (idx >= total) return;
  int f = idx % H;
  float v = fmaxf(acc[idx], 0.f);
  out[idx] = fmaf(v, mi[f], mi[128 + f]);
}

// ---------------- launch ----------------

extern "C" void kernel_launch(void* const* d_in, const int* in_sizes, int n_in,
                              void* d_out, int out_size, void* d_ws, size_t ws_size,
                              hipStream_t stream) {
  const float* x     = (const float*)d_in[0];
  const int*   ei    = (const int*)d_in[1];
  const float* W0    = (const float*)d_in[2];
  const float* b0    = (const float*)d_in[3];
  const float* Wr    = (const float*)d_in[4];
  const float* br    = (const float*)d_in[5];
  const float* gamma = (const float*)d_in[6];
  const float* beta  = (const float*)d_in[7];
  float* C = (float*)d_out;

  const int N = in_sizes[0] / FIN;
  const int E = in_sizes[1] / 2;
  const int* src = ei;
  const int* dst = ei + E;

  char* ws = (char*)d_ws;
  size_t off = 0;
  auto alloc = [&](size_t bytes) -> void* {
    void* p = ws + off;
    off = (off + bytes + 255) & ~(size_t)255;
    return p;
  };

  size_t NB = (size_t)N * H * sizeof(float);
  float* B0       = (float*)alloc(NB + 1024);   // T0 / h
  float* B1       = (float*)alloc(NB + 1024);   // T1 / T4
  float* B2       = (float*)alloc(NB + 1024);   // T2 / (T3 goes to B0)
  float* t1       = (float*)alloc((size_t)N * 2 * 4);
  float* t2       = (float*)alloc((size_t)N * 2 * 4);
  float* t3       = (float*)alloc((size_t)N * 2 * 4);
  float* t4       = (float*)alloc((size_t)N * 2 * 4);
  float* deg      = (float*)alloc((size_t)N * 4);
  int*   indeg    = (int*)alloc((size_t)N * 4);
  float* dinv     = (float*)alloc((size_t)N * 4);
  int*   incl     = (int*)alloc((size_t)N * 4);
  int*   bsum     = (int*)alloc(8192 * 4);
  int*   bscan    = (int*)alloc(8192 * 4);
  int*   offsets  = (int*)alloc((size_t)(N + 1) * 4);
  int*   cursor   = (int*)alloc((size_t)N * 4);
  int*   csr_src  = (int*)alloc((size_t)E * 4);
  float* csr_norm = (float*)alloc((size_t)E * 4);
  float* stats    = (float*)alloc(512 * 4);

  int gE = (E + 255) / 256;
  int gN = (N + 255) / 256;

  hipMemsetAsync(deg, 0, (size_t)N * 4, stream);
  hipMemsetAsync(indeg, 0, (size_t)N * 4, stream);

  deg_kernel<<<gE, 256, 0, stream>>>(src, dst, deg, indeg, E);
  dinv_kernel<<<gN, 256, 0, stream>>>(deg, dinv, N);
  scan_block<<<gN, 256, 0, stream>>>(indeg, incl, bsum, N);
  scan_sums<<<1, 256, 0, stream>>>(bsum, bscan, gN);
  finalize_offsets<<<gN, 256, 0, stream>>>(incl, indeg, bscan, offsets, cursor, N, E);
  build_csr<<<gE, 256, 0, stream>>>(src, dst, dinv, cursor, csr_src, csr_norm, E);

  // ---- layer 0 (F_IN = 2) ----
  prop2<<<gN, 256, 0, stream>>>(x,  x,  t1, offsets, csr_src, csr_norm, N, 0);
  prop2<<<gN, 256, 0, stream>>>(t1, x,  t2, offsets, csr_src, csr_norm, N, 1);
  prop2<<<gN, 256, 0, stream>>>(t2, t1, t3, offsets, csr_src, csr_norm, N, 1);
  prop2<<<gN, 256, 0, stream>>>(t3, t2, t4, offsets, csr_src, csr_norm, N, 1);
  layer0_out<<<(N + 31) / 32, 128, 0, stream>>>(x, t1, t2, t3, t4, W0, b0, C, N);
  hipMemsetAsync(stats, 0, 1024, stream);
  bn_stats<<<(N + 511) / 512, 128, 0, stream>>>(C, stats, N);
  bn_params<<<1, 128, 0, stream>>>(stats, gamma, beta, N);
  bn_final<<<(N * H + 255) / 256, 256, 0, stream>>>(C, stats + 256, B0, N * H);

  // ---- layers 1..4 (H = 100) ----
  int gG = (N + 63) / 64;
  int gP = (N + 1) / 2;
  for (int layer = 1; layer < 5; ++layer) {
    const float* Wl = Wr + (size_t)(layer - 1) * KORD * H * H;
    const float* bl = br + (size_t)(layer - 1) * H;
    // T0 = h (B0); T1 = prop(T0) -> B1; T2 = 2*prop(T1) - T0 -> B2
    prop_h<<<gP, 256, 0, stream>>>(B0, B0, B1, offsets, csr_src, csr_norm, N, 0);
    prop_h<<<gP, 256, 0, stream>>>(B1, B0, B2, offsets, csr_src, csr_norm, N, 1);
    // C = b + T0 W0 + T1 W1 + T2 W2  (registers across k, pure write)
    gemm_multi<<<gG, 256, 0, stream>>>(B0, B1, B2, 3, Wl, bl, C, N, 1);
    // T3 = 2*prop(T2) - T1 -> B0 (T0 dead) ; T4 = 2*prop(T3) - T2 -> B1 (T1 dead)
    prop_h<<<gP, 256, 0, stream>>>(B2, B1, B0, offsets, csr_src, csr_norm, N, 1);
    prop_h<<<gP, 256, 0, stream>>>(B0, B2, B1, offsets, csr_src, csr_norm, N, 1);
    // C += T3 W3 + T4 W4  (single RMW)
    gemm_multi<<<gG, 256, 0, stream>>>(B0, B1, B0, 2, Wl + 3 * H * H, bl, C, N, 0);
    // BN(relu(C)) -> next h (B0), or d_out for last layer
    hipMemsetAsync(stats, 0, 1024, stream);
    bn_stats<<<(N + 511) / 512, 128, 0, stream>>>(C, stats, N);
    bn_params<<<1, 128, 0, stream>>>(stats, gamma + (size_t)layer * H, beta + (size_t)layer * H, N);
    bn_final<<<(N * H + 255) / 256, 256, 0, stream>>>(C, stats + 256, (layer < 4) ? B0 : C, N * H);
  }
}

// Round 5
// 6838.814 us; speedup vs baseline: 3.4437x; 1.7779x over previous
//
#include <hip/hip_runtime.h>

#define H 100
#define FIN 2
#define KORD 5

typedef unsigned int uint32;
typedef unsigned short ushort16;
typedef __attribute__((ext_vector_type(8))) short s8v;   // 8 x bf16 (4 VGPRs)
typedef __attribute__((ext_vector_type(4))) float f4v;   // MFMA accumulator

__device__ __forceinline__ ushort16 f2b(float x) {  // fp32 -> bf16 RNE
  uint32 u = __float_as_uint(x);
  return (ushort16)((u + 0x7fffu + ((u >> 16) & 1u)) >> 16);
}
__device__ __forceinline__ float2 b2f2(uint32 v) {  // packed bf16x2 -> 2 fp32
  return make_float2(__uint_as_float(v << 16), __uint_as_float(v & 0xffff0000u));
}

// ---------------- graph setup ----------------

__global__ __launch_bounds__(256) void deg_kernel(const int* __restrict__ src, const int* __restrict__ dst,
                                                  float* __restrict__ deg, int* __restrict__ indeg, int E) {
  int e = blockIdx.x * 256 + threadIdx.x;
  if (e < E) {
    atomicAdd(&deg[src[e]], 1.0f);
    atomicAdd(&indeg[dst[e]], 1);
  }
}

__global__ __launch_bounds__(256) void dinv_kernel(const float* __restrict__ deg, float* __restrict__ dinv, int n) {
  int i = blockIdx.x * 256 + threadIdx.x;
  if (i < n) {
    float d = deg[i];
    dinv[i] = d > 0.f ? rsqrtf(fmaxf(d, 1.f)) : 0.f;
  }
}

__global__ __launch_bounds__(256) void scan_block(const int* __restrict__ in, int* __restrict__ incl,
                                                  int* __restrict__ bsum, int n) {
  __shared__ int s[256];
  int i = blockIdx.x * 256 + threadIdx.x;
  int v = (i < n) ? in[i] : 0;
  s[threadIdx.x] = v;
  __syncthreads();
  for (int d = 1; d < 256; d <<= 1) {
    int t = (threadIdx.x >= d) ? s[threadIdx.x - d] : 0;
    __syncthreads();
    s[threadIdx.x] += t;
    __syncthreads();
  }
  if (i < n) incl[i] = s[threadIdx.x];
  if (threadIdx.x == 255) bsum[blockIdx.x] = s[255];
}

__global__ __launch_bounds__(256) void scan_sums(const int* __restrict__ bsum, int* __restrict__ bscan, int nb) {
  __shared__ int s[256];
  __shared__ int carry;
  if (threadIdx.x == 0) carry = 0;
  __syncthreads();
  for (int base = 0; base < nb; base += 256) {
    int i = base + threadIdx.x;
    int v = (i < nb) ? bsum[i] : 0;
    s[threadIdx.x] = v;
    __syncthreads();
    for (int d = 1; d < 256; d <<= 1) {
      int t = (threadIdx.x >= d) ? s[threadIdx.x - d] : 0;
      __syncthreads();
      s[threadIdx.x] += t;
      __syncthreads();
    }
    int c = carry;
    if (i < nb) bscan[i] = s[threadIdx.x] + c;
    __syncthreads();
    if (threadIdx.x == 0) carry = c + s[255];
    __syncthreads();
  }
}

__global__ __launch_bounds__(256) void finalize_offsets(const int* __restrict__ incl, const int* __restrict__ indeg,
                                                        const int* __restrict__ bscan, int* __restrict__ offsets,
                                                        int* __restrict__ cursor, int n, int total) {
  int i = blockIdx.x * 256 + threadIdx.x;
  if (i < n) {
    int prev = (blockIdx.x > 0) ? bscan[blockIdx.x - 1] : 0;
    int excl = incl[i] - indeg[i] + prev;
    offsets[i] = excl;
    cursor[i] = excl;
  }
  if (i == 0) offsets[n] = total;
}

__global__ __launch_bounds__(256) void build_csr(const int* __restrict__ src, const int* __restrict__ dst,
                                                 const float* __restrict__ dinv, int* __restrict__ cursor,
                                                 int* __restrict__ csr_src, float* __restrict__ csr_norm, int E) {
  int e = blockIdx.x * 256 + threadIdx.x;
  if (e < E) {
    int s = src[e], d = dst[e];
    float nrm = -dinv[s] * dinv[d];
    int p = atomicAdd(&cursor[d], 1);
    csr_src[p] = s;
    csr_norm[p] = nrm;
  }
}

// ---------------- propagate ----------------

// F=2 props for layer 0 (thread per node), 4x unrolled
__global__ __launch_bounds__(256) void prop2(const float* __restrict__ h, const float* __restrict__ prev,
                                             float* __restrict__ out, const int* __restrict__ offs,
                                             const int* __restrict__ csrc, const float* __restrict__ cnorm,
                                             int n, int mode) {
  int i = blockIdx.x * 256 + threadIdx.x;
  if (i >= n) return;
  float a0 = 0.f, a1 = 0.f;
  int e0 = offs[i], e1 = offs[i + 1];
  int e = e0;
  for (; e + 4 <= e1; e += 4) {
    int s0 = csrc[e], s1 = csrc[e + 1], s2 = csrc[e + 2], s3 = csrc[e + 3];
    float w0 = cnorm[e], w1 = cnorm[e + 1], w2 = cnorm[e + 2], w3 = cnorm[e + 3];
    float x0 = h[2 * s0], y0 = h[2 * s0 + 1];
    float x1 = h[2 * s1], y1 = h[2 * s1 + 1];
    float x2 = h[2 * s2], y2 = h[2 * s2 + 1];
    float x3 = h[2 * s3], y3 = h[2 * s3 + 1];
    a0 = fmaf(w0, x0, a0); a1 = fmaf(w0, y0, a1);
    a0 = fmaf(w1, x1, a0); a1 = fmaf(w1, y1, a1);
    a0 = fmaf(w2, x2, a0); a1 = fmaf(w2, y2, a1);
    a0 = fmaf(w3, x3, a0); a1 = fmaf(w3, y3, a1);
  }
  for (; e < e1; ++e) {
    int s = csrc[e];
    float w = cnorm[e];
    a0 = fmaf(w, h[2 * s], a0);
    a1 = fmaf(w, h[2 * s + 1], a1);
  }
  if (mode) {
    a0 = 2.f * a0 - prev[2 * i];
    a1 = 2.f * a1 - prev[2 * i + 1];
  }
  out[2 * i] = a0;
  out[2 * i + 1] = a1;
}

// bf16 prop: T buffers are bf16 with row stride 128 (256 B rows).
// One wave per node, 4 nodes/block. Lane < 50 holds features (2*lane, 2*lane+1) as packed bf16x2.
// Gather = 200 B/edge. fp32 accumulate. mode1: out = 2*prop - prev (alias-safe, same-thread RAW).
__global__ __launch_bounds__(256) void prop_hb(const ushort16* __restrict__ h, const ushort16* __restrict__ prev,
                                               ushort16* __restrict__ out, const int* __restrict__ offs,
                                               const int* __restrict__ csrc, const float* __restrict__ cnorm,
                                               int n, int mode) {
  int lane = threadIdx.x & 63;
  int node = blockIdx.x * 4 + (threadIdx.x >> 6);
  if (node >= n) return;
  const uint32* hp = (const uint32*)h;  // pair view; row stride 64 pairs
  int e0 = offs[node], e1 = offs[node + 1];
  float ax = 0.f, ay = 0.f;
  bool act = lane < 50;
  int e = e0;
  for (; e + 4 <= e1; e += 4) {
    int s0 = csrc[e], s1 = csrc[e + 1], s2 = csrc[e + 2], s3 = csrc[e + 3];
    float w0 = cnorm[e], w1 = cnorm[e + 1], w2 = cnorm[e + 2], w3 = cnorm[e + 3];
    if (act) {
      uint32 v0 = hp[(size_t)s0 * 64 + lane];
      uint32 v1 = hp[(size_t)s1 * 64 + lane];
      uint32 v2 = hp[(size_t)s2 * 64 + lane];
      uint32 v3 = hp[(size_t)s3 * 64 + lane];
      float2 f0 = b2f2(v0), f1 = b2f2(v1), f2 = b2f2(v2), f3 = b2f2(v3);
      ax = fmaf(w0, f0.x, ax); ay = fmaf(w0, f0.y, ay);
      ax = fmaf(w1, f1.x, ax); ay = fmaf(w1, f1.y, ay);
      ax = fmaf(w2, f2.x, ax); ay = fmaf(w2, f2.y, ay);
      ax = fmaf(w3, f3.x, ax); ay = fmaf(w3, f3.y, ay);
    }
  }
  for (; e < e1; ++e) {
    int s = csrc[e];
    float w = cnorm[e];
    if (act) {
      float2 f0 = b2f2(hp[(size_t)s * 64 + lane]);
      ax = fmaf(w, f0.x, ax); ay = fmaf(w, f0.y, ay);
    }
  }
  if (act) {
    size_t o = (size_t)node * 64 + lane;
    float rx = ax, ry = ay;
    if (mode) {
      float2 p = b2f2(((const uint32*)prev)[o]);
      rx = 2.f * ax - p.x;
      ry = 2.f * ay - p.y;
    }
    ((uint32*)out)[o] = (uint32)f2b(rx) | ((uint32)f2b(ry) << 16);
  }
}

// ---------------- W repack: fp32 [mat][c][f] -> bf16 MFMA B-fragments ----------------
// Frag order: [mat][kc(4)][ft(7)][lane(64)][j(8)], value = W[c=kc*32+(lane>>4)*8+j][f=ft*16+(lane&15)]
// (zero-padded c>=100 or f>=100). One block (64 thr) per (mat,kc,ft); 16 B/thread write.

__global__ __launch_bounds__(64) void wconv(const float* __restrict__ Wr, ushort16* __restrict__ Wf) {
  int b = blockIdx.x;
  int l = threadIdx.x;
  int mat = b / 28, rem = b % 28;
  int kc = rem / 7, ft = rem % 7;
  const float* Wm = Wr + (size_t)mat * H * H;
  int c0 = kc * 32 + (l >> 4) * 8;
  int f = ft * 16 + (l & 15);
  ushort16 vals[8];
#pragma unroll
  for (int j = 0; j < 8; ++j) {
    int c = c0 + j;
    float v = (c < H && f < H) ? Wm[c * H + f] : 0.f;
    vals[j] = f2b(v);
  }
  uint4 pk;
  pk.x = (uint32)vals[0] | ((uint32)vals[1] << 16);
  pk.y = (uint32)vals[2] | ((uint32)vals[3] << 16);
  pk.z = (uint32)vals[4] | ((uint32)vals[5] << 16);
  pk.w = (uint32)vals[6] | ((uint32)vals[7] << 16);
  *(uint4*)(Wf + (size_t)b * 512 + l * 8) = pk;
}

// ---------------- MFMA GEMM: C[N,100] (+)= sum_k Tk @ Wk ----------------
// Block: 256 thr = 4 waves; wave handles 32 rows (2 m-subtiles) x 112 cols (7 f-tiles).
// A (bf16, stride-128 rows) loaded direct from global: 16 B/lane per frag, no LDS.
// B frags from Wf (repacked); K=128 (4 chunks of 32), zero-padded.

__global__ __launch_bounds__(256) void gemm_mfma(const ushort16* __restrict__ Ta, const ushort16* __restrict__ Tb,
                                                 const ushort16* __restrict__ Tc, int nk,
                                                 const ushort16* __restrict__ Wf, const float* __restrict__ bias,
                                                 float* __restrict__ C, int n, int initMode) {
  int t = threadIdx.x;
  int w = t >> 6, l = t & 63;
  int ml = l & 15, quad = l >> 4;
  int n0 = blockIdx.x * 128 + 32 * w;

  f4v acc[2][7];
  if (initMode) {
#pragma unroll
    for (int ft = 0; ft < 7; ++ft) {
      int f = ft * 16 + ml;
      float b = (f < H) ? bias[f] : 0.f;
      f4v v = {b, b, b, b};
      acc[0][ft] = v;
      acc[1][ft] = v;
    }
  } else {
#pragma unroll
    for (int s = 0; s < 2; ++s)
#pragma unroll
      for (int ft = 0; ft < 7; ++ft) {
        int f = ft * 16 + ml;
#pragma unroll
        for (int r = 0; r < 4; ++r) {
          int row = n0 + 16 * s + quad * 4 + r;
          acc[s][ft][r] = (f < H && row < n) ? C[(size_t)row * H + f] : 0.f;
        }
      }
  }

  for (int k = 0; k < nk; ++k) {
    const ushort16* T = (k == 0) ? Ta : ((k == 1) ? Tb : Tc);
#pragma unroll
    for (int kc = 0; kc < 4; ++kc) {
      s8v bfrag[7];
      const ushort16* wb = Wf + ((size_t)(k * 4 + kc) * 7) * 512 + l * 8;
#pragma unroll
      for (int ft = 0; ft < 7; ++ft) bfrag[ft] = *(const s8v*)(wb + ft * 512);
#pragma unroll
      for (int s = 0; s < 2; ++s) {
        const ushort16* ap = T + (size_t)(n0 + 16 * s + ml) * 128 + kc * 32 + quad * 8;
        s8v a = *(const s8v*)ap;
#pragma unroll
        for (int ft = 0; ft < 7; ++ft)
          acc[s][ft] = __builtin_amdgcn_mfma_f32_16x16x32_bf16(a, bfrag[ft], acc[s][ft], 0, 0, 0);
      }
    }
  }

#pragma unroll
  for (int s = 0; s < 2; ++s)
#pragma unroll
    for (int ft = 0; ft < 7; ++ft) {
      int f = ft * 16 + ml;
      if (f < H) {
#pragma unroll
        for (int r = 0; r < 4; ++r) {
          int row = n0 + 16 * s + quad * 4 + r;
          if (row < n) C[(size_t)row * H + f] = acc[s][ft][r];
        }
      }
    }
}

// ---------------- layer 0 dense part ----------------

__global__ __launch_bounds__(128) void layer0_out(const float* __restrict__ x, const float* __restrict__ t1,
                                                  const float* __restrict__ t2, const float* __restrict__ t3,
                                                  const float* __restrict__ t4, const float* __restrict__ W0,
                                                  const float* __restrict__ b0, float* __restrict__ C, int n) {
  int f = threadIdx.x;
  bool act = f < H;
  float w[10];
  float b = 0.f;
  if (act) {
#pragma unroll
    for (int j = 0; j < 10; ++j) w[j] = W0[j * H + f];
    b = b0[f];
  }
  int n0 = blockIdx.x * 32;
  int n1 = n0 + 32 < n ? n0 + 32 : n;
  for (int i = n0; i < n1; ++i) {
    if (!act) continue;
    float acc = b;
    acc = fmaf(x[2 * i],      w[0], acc);
    acc = fmaf(x[2 * i + 1],  w[1], acc);
    acc = fmaf(t1[2 * i],     w[2], acc);
    acc = fmaf(t1[2 * i + 1], w[3], acc);
    acc = fmaf(t2[2 * i],     w[4], acc);
    acc = fmaf(t2[2 * i + 1], w[5], acc);
    acc = fmaf(t3[2 * i],     w[6], acc);
    acc = fmaf(t3[2 * i + 1], w[7], acc);
    acc = fmaf(t4[2 * i],     w[8], acc);
    acc = fmaf(t4[2 * i + 1], w[9], acc);
    C[(size_t)i * H + f] = acc;
  }
}

// ---------------- batch norm ----------------

__global__ __launch_bounds__(128) void bn_stats(const float* __restrict__ acc, float* __restrict__ stats, int n) {
  int f = threadIdx.x;
  int n0 = blockIdx.x * 512;
  int n1 = n0 + 512 < n ? n0 + 512 : n;
  if (f < H) {
    float s = 0.f, s2 = 0.f;
    for (int i = n0; i < n1; ++i) {
      float v = fmaxf(acc[(size_t)i * H + f], 0.f);
      s += v;
      s2 = fmaf(v, v, s2);
    }
    atomicAdd(&stats[f], s);
    atomicAdd(&stats[128 + f], s2);
  }
}

__global__ __launch_bounds__(128) void bn_params(float* __restrict__ stats, const float* __restrict__ gamma,
                                                 const float* __restrict__ beta, int n) {
  int f = threadIdx.x;
  if (f >= H) return;
  float inv_n = 1.f / (float)n;
  float m = stats[f] * inv_n;
  float v = stats[128 + f] * inv_n - m * m;
  float is = rsqrtf(v + 1e-5f);
  float g = gamma[f] * is;
  stats[256 + f] = g;                // scale
  stats[384 + f] = beta[f] - m * g;  // shift
}

// fp32 out (final layer, in-place over C)
__global__ __launch_bounds__(256) void bn_final(const float* __restrict__ acc, const float* __restrict__ mi,
                                                float* __restrict__ out, int total) {
  int idx = blockIdx.x * 256 + threadIdx.x;
  if (idx >= total) return;
  int f = idx % H;
  float v = fmaxf(acc[idx], 0.f);
  out[idx] = fmaf(v, mi[f], mi[128 + f]);
}

// bf16 out with row stride 128 (h for next layer)
__global__ __launch_bounds__(256) void bn_final_bf16(const float* __restrict__ acc, const float* __restrict__ mi,
                                                     ushort16* __restrict__ out, int total) {
  int idx = blockIdx.x * 256 + threadIdx.x;
  if (idx >= total) return;
  int row = idx / H, f = idx - row * H;
  float v = fmaxf(acc[idx], 0.f);
  out[(size_t)row * 128 + f] = f2b(fmaf(v, mi[f], mi[128 + f]));
}

// ---------------- launch ----------------

extern "C" void kernel_launch(void* const* d_in, const int* in_sizes, int n_in,
                              void* d_out, int out_size, void* d_ws, size_t ws_size,
                              hipStream_t stream) {
  const float* x     = (const float*)d_in[0];
  const int*   ei    = (const int*)d_in[1];
  const float* W0    = (const float*)d_in[2];
  const float* b0    = (const float*)d_in[3];
  const float* Wr    = (const float*)d_in[4];
  const float* br    = (const float*)d_in[5];
  const float* gamma = (const float*)d_in[6];
  const float* beta  = (const float*)d_in[7];
  float* C = (float*)d_out;

  const int N = in_sizes[0] / FIN;
  const int E = in_sizes[1] / 2;
  const int* src = ei;
  const int* dst = ei + E;

  char* ws = (char*)d_ws;
  size_t off = 0;
  auto alloc = [&](size_t bytes) -> void* {
    void* p = ws + off;
    off = (off + bytes + 255) & ~(size_t)255;
    return p;
  };

  size_t TB = (size_t)N * 128 * sizeof(ushort16);  // bf16, stride-128 rows
  ushort16* B0     = (ushort16*)alloc(TB);
  ushort16* B1     = (ushort16*)alloc(TB);
  ushort16* B2     = (ushort16*)alloc(TB);
  ushort16* Wf     = (ushort16*)alloc((size_t)20 * 14336 * sizeof(ushort16));
  float* t1       = (float*)alloc((size_t)N * 2 * 4);
  float* t2       = (float*)alloc((size_t)N * 2 * 4);
  float* t3       = (float*)alloc((size_t)N * 2 * 4);
  float* t4       = (float*)alloc((size_t)N * 2 * 4);
  float* deg      = (float*)alloc((size_t)N * 4);
  int*   indeg    = (int*)alloc((size_t)N * 4);
  float* dinv     = (float*)alloc((size_t)N * 4);
  int*   incl     = (int*)alloc((size_t)N * 4);
  int*   bsum     = (int*)alloc(8192 * 4);
  int*   bscan    = (int*)alloc(8192 * 4);
  int*   offsets  = (int*)alloc((size_t)(N + 1) * 4);
  int*   cursor   = (int*)alloc((size_t)N * 4);
  int*   csr_src  = (int*)alloc((size_t)E * 4);
  float* csr_norm = (float*)alloc((size_t)E * 4);
  float* stats    = (float*)alloc(512 * 4);

  int gE = (E + 255) / 256;
  int gN = (N + 255) / 256;

  hipMemsetAsync(deg, 0, (size_t)N * 4, stream);
  hipMemsetAsync(indeg, 0, (size_t)N * 4, stream);

  deg_kernel<<<gE, 256, 0, stream>>>(src, dst, deg, indeg, E);
  dinv_kernel<<<gN, 256, 0, stream>>>(deg, dinv, N);
  scan_block<<<gN, 256, 0, stream>>>(indeg, incl, bsum, N);
  scan_sums<<<1, 256, 0, stream>>>(bsum, bscan, gN);
  finalize_offsets<<<gN, 256, 0, stream>>>(incl, indeg, bscan, offsets, cursor, N, E);
  build_csr<<<gE, 256, 0, stream>>>(src, dst, dinv, cursor, csr_src, csr_norm, E);
  wconv<<<20 * 28, 64, 0, stream>>>(Wr, Wf);

  // ---- layer 0 (F_IN = 2) ----
  prop2<<<gN, 256, 0, stream>>>(x,  x,  t1, offsets, csr_src, csr_norm, N, 0);
  prop2<<<gN, 256, 0, stream>>>(t1, x,  t2, offsets, csr_src, csr_norm, N, 1);
  prop2<<<gN, 256, 0, stream>>>(t2, t1, t3, offsets, csr_src, csr_norm, N, 1);
  prop2<<<gN, 256, 0, stream>>>(t3, t2, t4, offsets, csr_src, csr_norm, N, 1);
  layer0_out<<<(N + 31) / 32, 128, 0, stream>>>(x, t1, t2, t3, t4, W0, b0, C, N);
  hipMemsetAsync(stats, 0, 1024, stream);
  bn_stats<<<(N + 511) / 512, 128, 0, stream>>>(C, stats, N);
  bn_params<<<1, 128, 0, stream>>>(stats, gamma, beta, N);
  bn_final_bf16<<<(N * H + 255) / 256, 256, 0, stream>>>(C, stats + 256, B0, N * H);

  // ---- layers 1..4 (H = 100, bf16 T buffers, MFMA GEMMs) ----
  int gG = (N + 127) / 128;
  int gP = (N + 3) / 4;
  for (int layer = 1; layer < 5; ++layer) {
    const ushort16* WfL = Wf + (size_t)(layer - 1) * 5 * 14336;
    const float* bl = br + (size_t)(layer - 1) * H;
    // T0 = h (B0); T1 = prop(T0) -> B1; T2 = 2*prop(T1) - T0 -> B2
    prop_hb<<<gP, 256, 0, stream>>>(B0, B0, B1, offsets, csr_src, csr_norm, N, 0);
    prop_hb<<<gP, 256, 0, stream>>>(B1, B0, B2, offsets, csr_src, csr_norm, N, 1);
    // C = b + T0 W0 + T1 W1 + T2 W2
    gemm_mfma<<<gG, 256, 0, stream>>>(B0, B1, B2, 3, WfL, bl, C, N, 1);
    // T3 = 2*prop(T2) - T1 -> B0 ; T4 = 2*prop(T3) - T2 -> B1
    prop_hb<<<gP, 256, 0, stream>>>(B2, B1, B0, offsets, csr_src, csr_norm, N, 1);
    prop_hb<<<gP, 256, 0, stream>>>(B0, B2, B1, offsets, csr_src, csr_norm, N, 1);
    // C += T3 W3 + T4 W4
    gemm_mfma<<<gG, 256, 0, stream>>>(B0, B1, B0, 2, WfL + (size_t)3 * 14336, bl, C, N, 0);
    // BN(relu(C)) -> next h (bf16) or final output (fp32)
    hipMemsetAsync(stats, 0, 1024, stream);
    bn_stats<<<(N + 511) / 512, 128, 0, stream>>>(C, stats, N);
    bn_params<<<1, 128, 0, stream>>>(stats, gamma + (size_t)layer * H, beta + (size_t)layer * H, N);
    if (layer < 4)
      bn_final_bf16<<<(N * H + 255) / 256, 256, 0, stream>>>(C, stats + 256, B0, N * H);
    else
      bn_final<<<(N * H + 255) / 256, 256, 0, stream>>>(C, stats + 256, C, N * H);
  }
}